// Round 2
// baseline (5205.320 us; speedup 1.0000x reference)
//
#include <hip/hip_runtime.h>
#include <hip/hip_cooperative_groups.h>
#include <cstdint>
#include <cstddef>

namespace cg = cooperative_groups;

typedef unsigned short u16;
typedef __attribute__((ext_vector_type(8))) short bf16x8;
typedef __attribute__((ext_vector_type(4))) float f32x4;

#define NB 256
#define LL 128
#define DD 1024
#define HH 512
#define GG 2048   // 4H
#define NN 4096   // 2*GG
#define LINN 512

__device__ __forceinline__ u16 f2bf(float f) {
  unsigned u = __float_as_uint(f);
  u += 0x7fffu + ((u >> 16) & 1u);
  return (u16)(u >> 16);
}
__device__ __forceinline__ float bf2f(u16 h) {
  return __uint_as_float(((unsigned)h) << 16);
}
__device__ __forceinline__ float sigm(float x) { return 1.0f / (1.0f + __expf(-x)); }
__device__ __forceinline__ float tanh_fast(float x) {
  float a = fabsf(x);
  float e = __expf(-2.0f * a);
  float t = (1.0f - e) / (1.0f + e);
  return copysignf(t, x);
}
__device__ __forceinline__ void load_lds16(const void* g, void* l) {
  __builtin_amdgcn_global_load_lds(
      (const __attribute__((address_space(1))) void*)g,
      (__attribute__((address_space(3))) void*)l, 16, 0, 0);
}

// ---------------- K1: fp32 -> bf16 convert of x ----------------
__global__ __launch_bounds__(256) void conv_bf16(const float* __restrict__ in,
                                                 u16* __restrict__ out) {
  size_t i = ((size_t)blockIdx.x * 256 + threadIdx.x) * 8;
  float4 a = *(const float4*)(in + i);
  float4 b = *(const float4*)(in + i + 4);
  uint4 v;
  v.x = (unsigned)f2bf(a.x) | ((unsigned)f2bf(a.y) << 16);
  v.y = (unsigned)f2bf(a.z) | ((unsigned)f2bf(a.w) << 16);
  v.z = (unsigned)f2bf(b.x) | ((unsigned)f2bf(b.y) << 16);
  v.w = (unsigned)f2bf(b.z) | ((unsigned)f2bf(b.w) << 16);
  *(uint4*)(out + i) = v;
}

// ---------------- K2: permute+convert weights ----------------
// permuted row p = 4*j + gate  <-  original row gate*512 + j
__global__ __launch_bounds__(256) void prep_weights(
    const float* __restrict__ Wih_f, const float* __restrict__ Whh_f, const float* __restrict__ b_f,
    const float* __restrict__ Wih_b, const float* __restrict__ Whh_b, const float* __restrict__ b_b,
    u16* __restrict__ Wih_p, u16* __restrict__ Whh_p, float* __restrict__ bias_p) {
  int idx = blockIdx.x * 256 + threadIdx.x;   // 0 .. 2048*1024-1
  int p = idx >> 10, k = idx & 1023;
  int src = ((p & 3) << 9) | (p >> 2);
  Wih_p[(size_t)p * DD + k] = f2bf(Wih_f[(size_t)src * DD + k]);
  Wih_p[(size_t)GG * DD + (size_t)p * DD + k] = f2bf(Wih_b[(size_t)src * DD + k]);
  if (k < HH) {
    Whh_p[(size_t)p * HH + k] = f2bf(Whh_f[(size_t)src * HH + k]);
    Whh_p[(size_t)GG * HH + (size_t)p * HH + k] = f2bf(Whh_b[(size_t)src * HH + k]);
  }
  if (k == 0) { bias_p[p] = b_f[src]; bias_p[GG + p] = b_b[src]; }
}

// ---------------- K3: attention scores + masked softmax ----------------
__global__ __launch_bounds__(256) void attn_alpha(
    const float* __restrict__ x, const float* __restrict__ tword,
    const float* __restrict__ W_h, const float* __restrict__ b_tanh,
    const int* __restrict__ xlen, float* __restrict__ alpha) {
  int b = blockIdx.x, tid = threadIdx.x;
  int lane = tid & 63, wave = tid >> 6;
  __shared__ float wred[4];
  __shared__ float uvals[LL];
  const float* tw = tword + (size_t)b * 5 * DD;
  float acc = 0.f;
  for (int i = tid; i < 5 * DD; i += 256) acc += tw[i] * W_h[DD + (i & (DD - 1))];
  #pragma unroll
  for (int off = 32; off; off >>= 1) acc += __shfl_down(acc, off);
  if (lane == 0) wred[wave] = acc;
  __syncthreads();
  float twdot = (wred[0] + wred[1] + wred[2] + wred[3]) * 0.2f;
  int len = xlen[b];
  const float* xb = x + (size_t)b * LL * DD;
  for (int l = wave; l < LL; l += 4) {
    float s = 0.f;
    if (l < len) {
      const float* xr = xb + (size_t)l * DD;
      for (int k = lane * 4; k < DD; k += 256) {
        float4 xv = *(const float4*)(xr + k);
        float4 wv = *(const float4*)(W_h + k);
        s += xv.x * wv.x + xv.y * wv.y + xv.z * wv.z + xv.w * wv.w;
      }
      #pragma unroll
      for (int off = 32; off; off >>= 1) s += __shfl_down(s, off);
    }
    if (lane == 0) uvals[l] = (l < len) ? (s + twdot + b_tanh[l]) : -1000000.0f;
  }
  __syncthreads();
  if (wave == 0) {
    float u0 = uvals[lane], u1 = uvals[lane + 64];
    float m = fmaxf(u0, u1);
    #pragma unroll
    for (int off = 32; off; off >>= 1) m = fmaxf(m, __shfl_down(m, off));
    m = __shfl(m, 0);
    float e0 = __expf(u0 - m), e1 = __expf(u1 - m);
    float ssum = e0 + e1;
    #pragma unroll
    for (int off = 32; off; off >>= 1) ssum += __shfl_down(ssum, off);
    ssum = __shfl(ssum, 0);
    alpha[(size_t)b * LL + lane] = e0 / ssum;
    alpha[(size_t)b * LL + lane + 64] = e1 / ssum;
  }
}

// ---------------- K4: big input-projection GEMM ----------------
__global__ __launch_bounds__(256) void gemm_bt(
    const u16* __restrict__ A, const u16* __restrict__ Bw, u16* __restrict__ C) {
  __shared__ u16 At[128 * 64];
  __shared__ u16 Bt[128 * 64];
  const int tid = threadIdx.x;
  const int lane = tid & 63, wave = tid >> 6;
  const int m0 = blockIdx.y * 128, n0 = blockIdx.x * 128;
  const int wm = (wave >> 1) * 64, wn = (wave & 1) * 64;
  const int l15 = lane & 15, quad = lane >> 4;
  f32x4 acc[4][4] = {};
  const int rs = tid >> 3;
  const int slot = tid & 7;
  for (int kt = 0; kt < 16; ++kt) {
    __syncthreads();
    #pragma unroll
    for (int cc = 0; cc < 4; ++cc) {
      int row = cc * 32 + rs;
      int kseg = slot ^ (row & 7);
      const u16* ga = A + (size_t)(m0 + row) * DD + kt * 64 + kseg * 8;
      const u16* gb = Bw + (size_t)(n0 + row) * DD + kt * 64 + kseg * 8;
      load_lds16(ga, (char*)At + cc * 4096 + tid * 16);
      load_lds16(gb, (char*)Bt + cc * 4096 + tid * 16);
    }
    __syncthreads();
    #pragma unroll
    for (int ks = 0; ks < 2; ++ks) {
      bf16x8 av[4], bv[4];
      int kq = ks * 4 + quad;
      #pragma unroll
      for (int i = 0; i < 4; ++i) {
        int row = wm + i * 16 + l15;
        av[i] = *(const bf16x8*)(At + row * 64 + (kq ^ (row & 7)) * 8);
      }
      #pragma unroll
      for (int j = 0; j < 4; ++j) {
        int row = wn + j * 16 + l15;
        bv[j] = *(const bf16x8*)(Bt + row * 64 + (kq ^ (row & 7)) * 8);
      }
      #pragma unroll
      for (int i = 0; i < 4; ++i)
        #pragma unroll
        for (int j = 0; j < 4; ++j)
          acc[i][j] = __builtin_amdgcn_mfma_f32_16x16x32_bf16(av[i], bv[j], acc[i][j], 0, 0, 0);
    }
  }
  #pragma unroll
  for (int i = 0; i < 4; ++i) {
    #pragma unroll
    for (int r = 0; r < 4; ++r) {
      size_t row = (size_t)(m0 + wm + i * 16 + quad * 4 + r);
      u16* crow = C + row * NN + n0 + wn + l15;
      #pragma unroll
      for (int j = 0; j < 4; ++j) crow[j * 16] = f2bf(acc[i][j][r]);
    }
  }
}

// ---------------- K5: persistent cooperative recurrence (all 128 steps) ----
// 256 blocks = 2 dir x 8 btile(32 batches) x 16 ncol(128 perm cols = 32 hidden)
// W chunk resident in LDS for all steps; c/ctx in registers; h exchanged via
// global double buffer in MFMA A-fragment layout: hfrag[buf][dir][k>>3][b][k&7].
__global__ __launch_bounds__(256, 1) void lstm_persist(
    const u16* __restrict__ P, const u16* __restrict__ Whh_p,
    const float* __restrict__ bias_p, const float* __restrict__ alpha,
    const int* __restrict__ xlen, u16* __restrict__ hfrag,
    float* __restrict__ ctx) {
  __shared__ u16 Wl[128 * 512];        // XOR-swizzled k-segments
  __shared__ float gbuf[32][132];
  __shared__ float biasl[128];
  __shared__ int xl[32];
  cg::grid_group grid = cg::this_grid();
  const int tid = threadIdx.x;
  const int lane = tid & 63, wave = tid >> 6;
  const int l15 = lane & 15, quad = lane >> 4;
  const int bid = blockIdx.x;
  const int dir = bid >> 7, btile = (bid >> 4) & 7, ncol = bid & 15;

  // one-time: W chunk -> LDS (row = local perm col 0..127, K=512), swizzled
  {
    const u16* Wb = Whh_p + ((size_t)dir * GG + ncol * 128) * HH;
    for (int idx = tid; idx < 128 * 64; idx += 256) {
      int row = idx >> 6, seg = idx & 63;
      int sseg = seg ^ (row & 7);
      *(uint4*)&Wl[row * 512 + sseg * 8] = *(const uint4*)(Wb + (size_t)row * HH + seg * 8);
    }
  }
  if (tid < 128) biasl[tid] = bias_p[(size_t)dir * GG + ncol * 128 + tid];
  if (tid < 32) xl[tid] = xlen[btile * 32 + tid];

  // gate-phase ownership: thread = (b_local, jb) -> 4 hidden units
  const int b_local = tid >> 3, jb = tid & 7;
  const int b_glob = btile * 32 + b_local;
  const int jg0 = ncol * 32 + jb * 4;
  const size_t hslot = ((size_t)(dir * 64 + (jg0 >> 3)) * 256 + b_glob) * 8 + (jg0 & 7);
  // zero h[0] (buffer 0) — writer-ownership covers the whole buffer
  *(ushort4*)&hfrag[hslot] = make_ushort4(0, 0, 0, 0);

  float creg[4] = {0.f, 0.f, 0.f, 0.f};
  float ctxa[4] = {0.f, 0.f, 0.f, 0.f};

  // MFMA-phase decode: wave -> 16-batch subtile, 64-col half
  const int bt = wave >> 1, ch = wave & 1;
  const int b0 = btile * 32 + bt * 16;

  grid.sync();

  const size_t HBUF = (size_t)2 * 64 * 256 * 8;  // u16 elems per h buffer
  for (int s = 0; s < LL; ++s) {
    const u16* hc = hfrag + (size_t)(s & 1) * HBUF;
    u16* hx = hfrag + (size_t)((s + 1) & 1) * HBUF;

    // ---- GEMM: (16 batches) x (64 cols) x K=512 per wave ----
    bf16x8 av[16];
    #pragma unroll
    for (int ks = 0; ks < 16; ++ks) {
      const u16* ap = hc + ((size_t)(dir * 64 + ks * 4 + quad) * 256 + b0 + l15) * 8;
      av[ks] = *(const bf16x8*)ap;
    }
    f32x4 acc[4] = {};
    #pragma unroll
    for (int ks = 0; ks < 16; ++ks) {
      #pragma unroll
      for (int nt = 0; nt < 4; ++nt) {
        int r = ch * 64 + nt * 16 + l15;
        bf16x8 bv = *(const bf16x8*)&Wl[r * 512 + (((ks * 4 + quad)) ^ (r & 7)) * 8];
        acc[nt] = __builtin_amdgcn_mfma_f32_16x16x32_bf16(av[ks], bv, acc[nt], 0, 0, 0);
      }
    }
    #pragma unroll
    for (int nt = 0; nt < 4; ++nt)
      #pragma unroll
      for (int r = 0; r < 4; ++r)
        gbuf[bt * 16 + quad * 4 + r][ch * 64 + nt * 16 + l15] = acc[nt][r];
    __syncthreads();

    // ---- gates: thread = (b_local, jb), 4 hidden units ----
    const int len = xl[b_local];
    const bool valid = s < len;
    int t_b = dir ? (len - 1 - s) : s;
    if (t_b < 0) t_b = 0;
    const u16* Prow = P + ((size_t)b_glob * LL + t_b) * NN + (size_t)dir * GG + ncol * 128 + jb * 16;
    uint4 pa = *(const uint4*)(Prow);
    uint4 pb = *(const uint4*)(Prow + 8);
    unsigned pw[8] = {pa.x, pa.y, pa.z, pa.w, pb.x, pb.y, pb.z, pb.w};
    float al = valid ? alpha[(size_t)b_glob * LL + t_b] : 0.f;
    ushort4 hold = *(const ushort4*)&hc[hslot];
    unsigned short hv[4] = {hold.x, hold.y, hold.z, hold.w};
    #pragma unroll
    for (int u = 0; u < 4; ++u) {
      float4 gv = *(const float4*)&gbuf[b_local][jb * 16 + u * 4];
      float4 bb = *(const float4*)&biasl[jb * 16 + u * 4];
      float gi = gv.x + __uint_as_float(pw[u * 2] << 16) + bb.x;
      float gf = gv.y + __uint_as_float(pw[u * 2] & 0xffff0000u) + bb.y;
      float gz = gv.z + __uint_as_float(pw[u * 2 + 1] << 16) + bb.z;
      float go = gv.w + __uint_as_float(pw[u * 2 + 1] & 0xffff0000u) + bb.w;
      float ig = sigm(gi), fg = sigm(gf), zg = tanh_fast(gz), og = sigm(go);
      float cn = fg * creg[u] + ig * zg;
      float hn = og * tanh_fast(cn);
      if (valid) {
        creg[u] = cn;
        ctxa[u] += al * hn;
        hv[u] = f2bf(hn);
      }
    }
    *(ushort4*)&hx[hslot] = make_ushort4(hv[0], hv[1], hv[2], hv[3]);
    grid.sync();
  }

  #pragma unroll
  for (int u = 0; u < 4; ++u)
    ctx[(size_t)b_glob * (2 * HH) + dir * HH + jg0 + u] = ctxa[u];
}

// ---------------- K6: head ----------------
__global__ __launch_bounds__(256) void head(
    const float* __restrict__ ctx, const float* __restrict__ W_lin,
    const float* __restrict__ b_lin, const float* __restrict__ W_out,
    const float* __restrict__ b_out, float* __restrict__ out) {
  int b = blockIdx.x, tid = threadIdx.x;
  __shared__ float cbuf[2 * HH];
  __shared__ float lbuf[LINN];
  *(float4*)&cbuf[tid * 4] = *(const float4*)&ctx[(size_t)b * (2 * HH) + tid * 4];
  __syncthreads();
  #pragma unroll
  for (int rr = 0; rr < 2; ++rr) {
    int row = tid + rr * 256;
    const float* wr = W_lin + (size_t)row * (2 * HH);
    float s = 0.f;
    for (int k = 0; k < 2 * HH; k += 4) {
      float4 wv = *(const float4*)(wr + k);
      float4 cv = *(const float4*)(cbuf + k);
      s += wv.x * cv.x + wv.y * cv.y + wv.z * cv.z + wv.w * cv.w;
    }
    lbuf[row] = fmaxf(s + b_lin[row], 0.0f);
  }
  __syncthreads();
  int lane = tid & 63, wave = tid >> 6;
  if (wave < 3) {
    const float* wo = W_out + (size_t)wave * LINN;
    float s = 0.f;
    for (int k = lane; k < LINN; k += 64) s += lbuf[k] * wo[k];
    #pragma unroll
    for (int off = 32; off; off >>= 1) s += __shfl_down(s, off);
    if (lane == 0) out[(size_t)b * 3 + wave] = s + b_out[wave];
  }
}

extern "C" void kernel_launch(void* const* d_in, const int* in_sizes, int n_in,
                              void* d_out, int out_size, void* d_ws, size_t ws_size,
                              hipStream_t stream) {
  (void)in_sizes; (void)n_in; (void)out_size; (void)ws_size;
  const float* x      = (const float*)d_in[0];
  const int*   xlen   = (const int*)d_in[1];
  const float* tword  = (const float*)d_in[3];
  const float* Wih_f  = (const float*)d_in[5];
  const float* Whh_f  = (const float*)d_in[6];
  const float* b_f    = (const float*)d_in[7];
  const float* Wih_b  = (const float*)d_in[8];
  const float* Whh_b  = (const float*)d_in[9];
  const float* b_b    = (const float*)d_in[10];
  const float* W_h    = (const float*)d_in[11];
  const float* b_tanh = (const float*)d_in[12];
  const float* W_lin  = (const float*)d_in[13];
  const float* b_lin  = (const float*)d_in[14];
  const float* W_out  = (const float*)d_in[15];
  const float* b_out  = (const float*)d_in[16];
  float* out = (float*)d_out;

  char* w = (char*)d_ws;
  u16* xe_bf = (u16*)w;      w += (size_t)NB * LL * DD * 2;     // 64 MB
  u16* Pbuf  = (u16*)w;      w += (size_t)NB * LL * NN * 2;     // 256 MB
  u16* Wih_p = (u16*)w;      w += (size_t)2 * GG * DD * 2;      // 8 MB
  u16* Whh_p = (u16*)w;      w += (size_t)2 * GG * HH * 2;      // 4 MB
  float* bias_p = (float*)w; w += (size_t)2 * GG * 4;
  float* alphaW = (float*)w; w += (size_t)NB * LL * 4;
  u16* hfrag = (u16*)w;      w += (size_t)2 * 2 * 64 * 256 * 8 * 2;  // 1 MB
  float* ctxb = (float*)w;   w += (size_t)NB * 2 * HH * 4;

  conv_bf16<<<16384, 256, 0, stream>>>(x, xe_bf);
  prep_weights<<<8192, 256, 0, stream>>>(Wih_f, Whh_f, b_f, Wih_b, Whh_b, b_b,
                                         Wih_p, Whh_p, bias_p);
  attn_alpha<<<256, 256, 0, stream>>>(x, tword, W_h, b_tanh, xlen, alphaW);
  gemm_bt<<<dim3(32, 256), 256, 0, stream>>>(xe_bf, Wih_p, Pbuf);

  {
    const u16* Pc = Pbuf;
    const u16* Wc = Whh_p;
    const float* bc = bias_p;
    const float* ac = alphaW;
    const int* lc = xlen;
    u16* hc = hfrag;
    float* cc = ctxb;
    void* kargs[] = {&Pc, &Wc, &bc, &ac, &lc, &hc, &cc};
    hipLaunchCooperativeKernel((const void*)lstm_persist, dim3(256), dim3(256),
                               kargs, 0, stream);
  }

  head<<<256, 256, 0, stream>>>(ctxb, W_lin, b_lin, W_out, b_out, out);
}

// Round 3
// 2570.833 us; speedup vs baseline: 2.0248x; 2.0248x over previous
//
#include <hip/hip_runtime.h>
#include <cstdint>
#include <cstddef>

typedef unsigned short u16;
typedef __attribute__((ext_vector_type(8))) short bf16x8;
typedef __attribute__((ext_vector_type(4))) float f32x4;

#define NB 256
#define LL 128
#define DD 1024
#define HH 512
#define GG 2048   // 4H
#define NN 4096   // 2*GG
#define LINN 512

__device__ __forceinline__ u16 f2bf(float f) {
  unsigned u = __float_as_uint(f);
  u += 0x7fffu + ((u >> 16) & 1u);
  return (u16)(u >> 16);
}
__device__ __forceinline__ float sigm(float x) { return 1.0f / (1.0f + __expf(-x)); }
__device__ __forceinline__ float tanh_fast(float x) {
  float a = fabsf(x);
  float e = __expf(-2.0f * a);
  float t = (1.0f - e) / (1.0f + e);
  return copysignf(t, x);
}
__device__ __forceinline__ void load_lds16(const void* g, void* l) {
  __builtin_amdgcn_global_load_lds(
      (const __attribute__((address_space(1))) void*)g,
      (__attribute__((address_space(3))) void*)l, 16, 0, 0);
}

// ---------------- K1: fp32 -> bf16 convert of x ----------------
__global__ __launch_bounds__(256) void conv_bf16(const float* __restrict__ in,
                                                 u16* __restrict__ out) {
  size_t i = ((size_t)blockIdx.x * 256 + threadIdx.x) * 8;
  float4 a = *(const float4*)(in + i);
  float4 b = *(const float4*)(in + i + 4);
  uint4 v;
  v.x = (unsigned)f2bf(a.x) | ((unsigned)f2bf(a.y) << 16);
  v.y = (unsigned)f2bf(a.z) | ((unsigned)f2bf(a.w) << 16);
  v.z = (unsigned)f2bf(b.x) | ((unsigned)f2bf(b.y) << 16);
  v.w = (unsigned)f2bf(b.z) | ((unsigned)f2bf(b.w) << 16);
  *(uint4*)(out + i) = v;
}

// ---------------- K2: permute+convert weights ----------------
// permuted row p = 4*j + gate  <-  original row gate*512 + j
__global__ __launch_bounds__(256) void prep_weights(
    const float* __restrict__ Wih_f, const float* __restrict__ Whh_f, const float* __restrict__ b_f,
    const float* __restrict__ Wih_b, const float* __restrict__ Whh_b, const float* __restrict__ b_b,
    u16* __restrict__ Wih_p, u16* __restrict__ Whh_p, float* __restrict__ bias_p) {
  int idx = blockIdx.x * 256 + threadIdx.x;   // 0 .. 2048*1024-1
  int p = idx >> 10, k = idx & 1023;
  int src = ((p & 3) << 9) | (p >> 2);
  Wih_p[(size_t)p * DD + k] = f2bf(Wih_f[(size_t)src * DD + k]);
  Wih_p[(size_t)GG * DD + (size_t)p * DD + k] = f2bf(Wih_b[(size_t)src * DD + k]);
  if (k < HH) {
    Whh_p[(size_t)p * HH + k] = f2bf(Whh_f[(size_t)src * HH + k]);
    Whh_p[(size_t)GG * HH + (size_t)p * HH + k] = f2bf(Whh_b[(size_t)src * HH + k]);
  }
  if (k == 0) { bias_p[p] = b_f[src]; bias_p[GG + p] = b_b[src]; }
}

// ---------------- K3: attention scores + masked softmax ----------------
__global__ __launch_bounds__(256) void attn_alpha(
    const float* __restrict__ x, const float* __restrict__ tword,
    const float* __restrict__ W_h, const float* __restrict__ b_tanh,
    const int* __restrict__ xlen, float* __restrict__ alpha) {
  int b = blockIdx.x, tid = threadIdx.x;
  int lane = tid & 63, wave = tid >> 6;
  __shared__ float wred[4];
  __shared__ float uvals[LL];
  const float* tw = tword + (size_t)b * 5 * DD;
  float acc = 0.f;
  for (int i = tid; i < 5 * DD; i += 256) acc += tw[i] * W_h[DD + (i & (DD - 1))];
  #pragma unroll
  for (int off = 32; off; off >>= 1) acc += __shfl_down(acc, off);
  if (lane == 0) wred[wave] = acc;
  __syncthreads();
  float twdot = (wred[0] + wred[1] + wred[2] + wred[3]) * 0.2f;
  int len = xlen[b];
  const float* xb = x + (size_t)b * LL * DD;
  for (int l = wave; l < LL; l += 4) {
    float s = 0.f;
    if (l < len) {
      const float* xr = xb + (size_t)l * DD;
      for (int k = lane * 4; k < DD; k += 256) {
        float4 xv = *(const float4*)(xr + k);
        float4 wv = *(const float4*)(W_h + k);
        s += xv.x * wv.x + xv.y * wv.y + xv.z * wv.z + xv.w * wv.w;
      }
      #pragma unroll
      for (int off = 32; off; off >>= 1) s += __shfl_down(s, off);
    }
    if (lane == 0) uvals[l] = (l < len) ? (s + twdot + b_tanh[l]) : -1000000.0f;
  }
  __syncthreads();
  if (wave == 0) {
    float u0 = uvals[lane], u1 = uvals[lane + 64];
    float m = fmaxf(u0, u1);
    #pragma unroll
    for (int off = 32; off; off >>= 1) m = fmaxf(m, __shfl_down(m, off));
    m = __shfl(m, 0);
    float e0 = __expf(u0 - m), e1 = __expf(u1 - m);
    float ssum = e0 + e1;
    #pragma unroll
    for (int off = 32; off; off >>= 1) ssum += __shfl_down(ssum, off);
    ssum = __shfl(ssum, 0);
    alpha[(size_t)b * LL + lane] = e0 / ssum;
    alpha[(size_t)b * LL + lane + 64] = e1 / ssum;
  }
}

// ---------------- K4: big input-projection GEMM ----------------
__global__ __launch_bounds__(256) void gemm_bt(
    const u16* __restrict__ A, const u16* __restrict__ Bw, u16* __restrict__ C) {
  __shared__ u16 At[128 * 64];
  __shared__ u16 Bt[128 * 64];
  const int tid = threadIdx.x;
  const int lane = tid & 63, wave = tid >> 6;
  const int m0 = blockIdx.y * 128, n0 = blockIdx.x * 128;
  const int wm = (wave >> 1) * 64, wn = (wave & 1) * 64;
  const int l15 = lane & 15, quad = lane >> 4;
  f32x4 acc[4][4] = {};
  const int rs = tid >> 3;
  const int slot = tid & 7;
  for (int kt = 0; kt < 16; ++kt) {
    __syncthreads();
    #pragma unroll
    for (int cc = 0; cc < 4; ++cc) {
      int row = cc * 32 + rs;
      int kseg = slot ^ (row & 7);
      const u16* ga = A + (size_t)(m0 + row) * DD + kt * 64 + kseg * 8;
      const u16* gb = Bw + (size_t)(n0 + row) * DD + kt * 64 + kseg * 8;
      load_lds16(ga, (char*)At + cc * 4096 + tid * 16);
      load_lds16(gb, (char*)Bt + cc * 4096 + tid * 16);
    }
    __syncthreads();
    #pragma unroll
    for (int ks = 0; ks < 2; ++ks) {
      bf16x8 av[4], bv[4];
      int kq = ks * 4 + quad;
      #pragma unroll
      for (int i = 0; i < 4; ++i) {
        int row = wm + i * 16 + l15;
        av[i] = *(const bf16x8*)(At + row * 64 + (kq ^ (row & 7)) * 8);
      }
      #pragma unroll
      for (int j = 0; j < 4; ++j) {
        int row = wn + j * 16 + l15;
        bv[j] = *(const bf16x8*)(Bt + row * 64 + (kq ^ (row & 7)) * 8);
      }
      #pragma unroll
      for (int i = 0; i < 4; ++i)
        #pragma unroll
        for (int j = 0; j < 4; ++j)
          acc[i][j] = __builtin_amdgcn_mfma_f32_16x16x32_bf16(av[i], bv[j], acc[i][j], 0, 0, 0);
    }
  }
  #pragma unroll
  for (int i = 0; i < 4; ++i) {
    #pragma unroll
    for (int r = 0; r < 4; ++r) {
      size_t row = (size_t)(m0 + wm + i * 16 + quad * 4 + r);
      u16* crow = C + row * NN + n0 + wn + l15;
      #pragma unroll
      for (int j = 0; j < 4; ++j) crow[j * 16] = f2bf(acc[i][j][r]);
    }
  }
}

// ---------------- K5: persistent recurrence, 16-block group barriers -------
// 256 blocks = 2 dir x 8 btile(32 batches) x 16 ncol(128 perm cols).
// Sync scope: only the 16 ncol-blocks sharing (dir,btile). One-shot counter
// per (group, step), single-phase: arrive via atomicAdd, spin until ==16.
// Double-buffered h is WAR-safe: step-s reads precede step-s arrive; step-s+1
// writes happen only after barrier(s) completes.
__global__ __launch_bounds__(256, 1) void lstm_persist(
    const u16* __restrict__ P, const u16* __restrict__ Whh_p,
    const float* __restrict__ bias_p, const float* __restrict__ alpha,
    const int* __restrict__ xlen, u16* __restrict__ hfrag,
    float* __restrict__ ctx, int* __restrict__ bar) {
  __shared__ u16 Wl[128 * 512];        // XOR-swizzled k-segments
  __shared__ float gbuf[32][132];
  __shared__ float biasl[128];
  __shared__ int xl[32];
  const int tid = threadIdx.x;
  const int lane = tid & 63, wave = tid >> 6;
  const int l15 = lane & 15, quad = lane >> 4;
  const int bid = blockIdx.x;
  const int dir = bid >> 7, btile = (bid >> 4) & 7, ncol = bid & 15;
  const int gid = bid >> 4;            // (dir, btile) group, 16 members

  // one-time: W chunk -> LDS (row = local perm col 0..127, K=512), swizzled
  {
    const u16* Wb = Whh_p + ((size_t)dir * GG + ncol * 128) * HH;
    for (int idx = tid; idx < 128 * 64; idx += 256) {
      int row = idx >> 6, seg = idx & 63;
      int sseg = seg ^ (row & 7);
      *(uint4*)&Wl[row * 512 + sseg * 8] = *(const uint4*)(Wb + (size_t)row * HH + seg * 8);
    }
  }
  if (tid < 128) biasl[tid] = bias_p[(size_t)dir * GG + ncol * 128 + tid];
  if (tid < 32) xl[tid] = xlen[btile * 32 + tid];
  __syncthreads();

  // gate-phase ownership: thread = (b_local, jb) -> 4 hidden units
  const int b_local = tid >> 3, jb = tid & 7;
  const int b_glob = btile * 32 + b_local;
  const int jg0 = ncol * 32 + jb * 4;
  const size_t hslot = ((size_t)(dir * 64 + (jg0 >> 3)) * 256 + b_glob) * 8 + (jg0 & 7);
  const int len = xl[b_local];

  float creg[4] = {0.f, 0.f, 0.f, 0.f};
  float ctxa[4] = {0.f, 0.f, 0.f, 0.f};
  u16 hv[4] = {0, 0, 0, 0};            // carried h (registers), no reload

  // MFMA-phase decode: wave -> 16-batch subtile, 64-col half
  const int bt = wave >> 1, ch = wave & 1;
  const int b0 = btile * 32 + bt * 16;

  // prefetch P/alpha for step 0
  const u16* Pbase = P + (size_t)b_glob * LL * NN + (size_t)dir * GG + ncol * 128 + jb * 16;
  int t0 = dir ? (len - 1) : 0;
  t0 = min(max(t0, 0), LL - 1);
  uint4 pa = *(const uint4*)(Pbase + (size_t)t0 * NN);
  uint4 pb = *(const uint4*)(Pbase + (size_t)t0 * NN + 8);
  float al = alpha[(size_t)b_glob * LL + t0];

  const size_t HBUF = (size_t)2 * 64 * 256 * 8;  // u16 elems per h buffer
  for (int s = 0; s < LL; ++s) {
    const u16* hc = hfrag + (size_t)(s & 1) * HBUF;   // buffer 0 pre-zeroed by host memset
    u16* hx = hfrag + (size_t)((s + 1) & 1) * HBUF;

    // ---- GEMM: (16 batches) x (64 cols) x K=512 per wave ----
    bf16x8 av[16];
    #pragma unroll
    for (int ks = 0; ks < 16; ++ks)
      av[ks] = *(const bf16x8*)(hc + ((size_t)(dir * 64 + ks * 4 + quad) * 256 + b0 + l15) * 8);
    f32x4 acc[4] = {};
    #pragma unroll
    for (int ks = 0; ks < 16; ++ks) {
      #pragma unroll
      for (int nt = 0; nt < 4; ++nt) {
        int r = ch * 64 + nt * 16 + l15;
        bf16x8 bv = *(const bf16x8*)&Wl[r * 512 + ((ks * 4 + quad) ^ (r & 7)) * 8];
        acc[nt] = __builtin_amdgcn_mfma_f32_16x16x32_bf16(av[ks], bv, acc[nt], 0, 0, 0);
      }
    }
    #pragma unroll
    for (int nt = 0; nt < 4; ++nt)
      #pragma unroll
      for (int r = 0; r < 4; ++r)
        gbuf[bt * 16 + quad * 4 + r][ch * 64 + nt * 16 + l15] = acc[nt][r];
    __syncthreads();

    // ---- gates ----
    const bool valid = s < len;
    unsigned pw[8] = {pa.x, pa.y, pa.z, pa.w, pb.x, pb.y, pb.z, pb.w};
    #pragma unroll
    for (int u = 0; u < 4; ++u) {
      float4 gv = *(const float4*)&gbuf[b_local][jb * 16 + u * 4];
      float4 bb = *(const float4*)&biasl[jb * 16 + u * 4];
      float gi = gv.x + __uint_as_float(pw[u * 2] << 16) + bb.x;
      float gf = gv.y + __uint_as_float(pw[u * 2] & 0xffff0000u) + bb.y;
      float gz = gv.z + __uint_as_float(pw[u * 2 + 1] << 16) + bb.z;
      float go = gv.w + __uint_as_float(pw[u * 2 + 1] & 0xffff0000u) + bb.w;
      float ig = sigm(gi), fg = sigm(gf), zg = tanh_fast(gz), og = sigm(go);
      float cn = fg * creg[u] + ig * zg;
      float hn = og * tanh_fast(cn);
      if (valid) {
        creg[u] = cn;
        ctxa[u] += al * hn;
        hv[u] = f2bf(hn);
      }
    }
    *(ushort4*)&hx[hslot] = make_ushort4(hv[0], hv[1], hv[2], hv[3]);

    // ---- prefetch P/alpha for step s+1 (overlaps barrier) ----
    int tn = dir ? (len - 2 - s) : (s + 1);
    tn = min(max(tn, 0), LL - 1);
    uint4 npa = *(const uint4*)(Pbase + (size_t)tn * NN);
    uint4 npb = *(const uint4*)(Pbase + (size_t)tn * NN + 8);
    float nal = alpha[(size_t)b_glob * LL + tn];

    // ---- group barrier (skip after last step) ----
    if (s < LL - 1) {
      __syncthreads();   // drains vmcnt: all h stores in L2; covers gbuf WAR
      if (tid == 0) {
        __builtin_amdgcn_fence(__ATOMIC_RELEASE, "agent");
        int* c = bar + ((size_t)gid * LL + s) * 32;   // 128B-spaced one-shot counter
        __hip_atomic_fetch_add(c, 1, __ATOMIC_RELAXED, __HIP_MEMORY_SCOPE_AGENT);
        while (__hip_atomic_load(c, __ATOMIC_RELAXED, __HIP_MEMORY_SCOPE_AGENT) < 16)
          __builtin_amdgcn_s_sleep(1);
        __builtin_amdgcn_fence(__ATOMIC_ACQUIRE, "agent");
      }
      __syncthreads();
    }
    pa = npa; pb = npb; al = nal;
  }

  #pragma unroll
  for (int u = 0; u < 4; ++u)
    ctx[(size_t)b_glob * (2 * HH) + dir * HH + jg0 + u] = ctxa[u];
}

// ---------------- K6: head ----------------
__global__ __launch_bounds__(256) void head(
    const float* __restrict__ ctx, const float* __restrict__ W_lin,
    const float* __restrict__ b_lin, const float* __restrict__ W_out,
    const float* __restrict__ b_out, float* __restrict__ out) {
  int b = blockIdx.x, tid = threadIdx.x;
  __shared__ float cbuf[2 * HH];
  __shared__ float lbuf[LINN];
  *(float4*)&cbuf[tid * 4] = *(const float4*)&ctx[(size_t)b * (2 * HH) + tid * 4];
  __syncthreads();
  #pragma unroll
  for (int rr = 0; rr < 2; ++rr) {
    int row = tid + rr * 256;
    const float* wr = W_lin + (size_t)row * (2 * HH);
    float s = 0.f;
    for (int k = 0; k < 2 * HH; k += 4) {
      float4 wv = *(const float4*)(wr + k);
      float4 cv = *(const float4*)(cbuf + k);
      s += wv.x * cv.x + wv.y * cv.y + wv.z * cv.z + wv.w * cv.w;
    }
    lbuf[row] = fmaxf(s + b_lin[row], 0.0f);
  }
  __syncthreads();
  int lane = tid & 63, wave = tid >> 6;
  if (wave < 3) {
    const float* wo = W_out + (size_t)wave * LINN;
    float s = 0.f;
    for (int k = lane; k < LINN; k += 64) s += lbuf[k] * wo[k];
    #pragma unroll
    for (int off = 32; off; off >>= 1) s += __shfl_down(s, off);
    if (lane == 0) out[(size_t)b * 3 + wave] = s + b_out[wave];
  }
}

extern "C" void kernel_launch(void* const* d_in, const int* in_sizes, int n_in,
                              void* d_out, int out_size, void* d_ws, size_t ws_size,
                              hipStream_t stream) {
  (void)in_sizes; (void)n_in; (void)out_size; (void)ws_size;
  const float* x      = (const float*)d_in[0];
  const int*   xlen   = (const int*)d_in[1];
  const float* tword  = (const float*)d_in[3];
  const float* Wih_f  = (const float*)d_in[5];
  const float* Whh_f  = (const float*)d_in[6];
  const float* b_f    = (const float*)d_in[7];
  const float* Wih_b  = (const float*)d_in[8];
  const float* Whh_b  = (const float*)d_in[9];
  const float* b_b    = (const float*)d_in[10];
  const float* W_h    = (const float*)d_in[11];
  const float* b_tanh = (const float*)d_in[12];
  const float* W_lin  = (const float*)d_in[13];
  const float* b_lin  = (const float*)d_in[14];
  const float* W_out  = (const float*)d_in[15];
  const float* b_out  = (const float*)d_in[16];
  float* out = (float*)d_out;

  char* w = (char*)d_ws;
  u16* xe_bf = (u16*)w;      w += (size_t)NB * LL * DD * 2;     // 64 MB
  u16* Pbuf  = (u16*)w;      w += (size_t)NB * LL * NN * 2;     // 256 MB
  u16* Wih_p = (u16*)w;      w += (size_t)2 * GG * DD * 2;      // 8 MB
  u16* Whh_p = (u16*)w;      w += (size_t)2 * GG * HH * 2;      // 4 MB
  float* bias_p = (float*)w; w += (size_t)2 * GG * 4;
  float* alphaW = (float*)w; w += (size_t)NB * LL * 4;
  u16* hfrag = (u16*)w;      w += (size_t)2 * 2 * 64 * 256 * 8 * 2;  // 1 MB
  float* ctxb = (float*)w;   w += (size_t)NB * 2 * HH * 4;
  int* barW  = (int*)w;      w += (size_t)16 * LL * 32 * 4;     // 256 KB one-shot counters

  // buffer 0 of hfrag must be zero (h_0 = 0); counters must start at 0
  hipMemsetAsync(hfrag, 0, (size_t)2 * 64 * 256 * 8 * 2, stream);
  hipMemsetAsync(barW, 0, (size_t)16 * LL * 32 * 4, stream);

  conv_bf16<<<16384, 256, 0, stream>>>(x, xe_bf);
  prep_weights<<<8192, 256, 0, stream>>>(Wih_f, Whh_f, b_f, Wih_b, Whh_b, b_b,
                                         Wih_p, Whh_p, bias_p);
  attn_alpha<<<256, 256, 0, stream>>>(x, tword, W_h, b_tanh, xlen, alphaW);
  gemm_bt<<<dim3(32, 256), 256, 0, stream>>>(xe_bf, Wih_p, Pbuf);

  {
    const u16* Pc = Pbuf;
    const u16* Wc = Whh_p;
    const float* bc = bias_p;
    const float* ac = alphaW;
    const int* lc = xlen;
    u16* hc = hfrag;
    float* cc = ctxb;
    int* brc = barW;
    void* kargs[] = {&Pc, &Wc, &bc, &ac, &lc, &hc, &cc, &brc};
    hipLaunchCooperativeKernel((const void*)lstm_persist, dim3(256), dim3(256),
                               kargs, 0, stream);
  }

  head<<<256, 256, 0, stream>>>(ctxb, W_lin, b_lin, W_out, b_out, out);
}

// Round 4
// 1306.647 us; speedup vs baseline: 3.9837x; 1.9675x over previous
//
#include <hip/hip_runtime.h>
#include <cstdint>
#include <cstddef>

typedef unsigned short u16;
typedef unsigned long long ull;
typedef __attribute__((ext_vector_type(8))) short bf16x8;
typedef __attribute__((ext_vector_type(4))) float f32x4;

#define NB 256
#define LL 128
#define DD 1024
#define HH 512
#define GG 2048   // 4H
#define NN 4096   // 2*GG
#define LINN 512

__device__ __forceinline__ u16 f2bf(float f) {
  unsigned u = __float_as_uint(f);
  u += 0x7fffu + ((u >> 16) & 1u);
  return (u16)(u >> 16);
}
__device__ __forceinline__ float sigm(float x) { return 1.0f / (1.0f + __expf(-x)); }
__device__ __forceinline__ float tanh_fast(float x) {
  float a = fabsf(x);
  float e = __expf(-2.0f * a);
  float t = (1.0f - e) / (1.0f + e);
  return copysignf(t, x);
}
__device__ __forceinline__ void load_lds16(const void* g, void* l) {
  __builtin_amdgcn_global_load_lds(
      (const __attribute__((address_space(1))) void*)g,
      (__attribute__((address_space(3))) void*)l, 16, 0, 0);
}

// ---------------- K1: fp32 -> bf16 convert of x ----------------
__global__ __launch_bounds__(256) void conv_bf16(const float* __restrict__ in,
                                                 u16* __restrict__ out) {
  size_t i = ((size_t)blockIdx.x * 256 + threadIdx.x) * 8;
  float4 a = *(const float4*)(in + i);
  float4 b = *(const float4*)(in + i + 4);
  uint4 v;
  v.x = (unsigned)f2bf(a.x) | ((unsigned)f2bf(a.y) << 16);
  v.y = (unsigned)f2bf(a.z) | ((unsigned)f2bf(a.w) << 16);
  v.z = (unsigned)f2bf(b.x) | ((unsigned)f2bf(b.y) << 16);
  v.w = (unsigned)f2bf(b.z) | ((unsigned)f2bf(b.w) << 16);
  *(uint4*)(out + i) = v;
}

// ---------------- K2: permute+convert weights ----------------
// permuted row p = 4*j + gate  <-  original row gate*512 + j
__global__ __launch_bounds__(256) void prep_weights(
    const float* __restrict__ Wih_f, const float* __restrict__ Whh_f, const float* __restrict__ b_f,
    const float* __restrict__ Wih_b, const float* __restrict__ Whh_b, const float* __restrict__ b_b,
    u16* __restrict__ Wih_p, u16* __restrict__ Whh_p, float* __restrict__ bias_p) {
  int idx = blockIdx.x * 256 + threadIdx.x;   // 0 .. 2048*1024-1
  int p = idx >> 10, k = idx & 1023;
  int src = ((p & 3) << 9) | (p >> 2);
  Wih_p[(size_t)p * DD + k] = f2bf(Wih_f[(size_t)src * DD + k]);
  Wih_p[(size_t)GG * DD + (size_t)p * DD + k] = f2bf(Wih_b[(size_t)src * DD + k]);
  if (k < HH) {
    Whh_p[(size_t)p * HH + k] = f2bf(Whh_f[(size_t)src * HH + k]);
    Whh_p[(size_t)GG * HH + (size_t)p * HH + k] = f2bf(Whh_b[(size_t)src * HH + k]);
  }
  if (k == 0) { bias_p[p] = b_f[src]; bias_p[GG + p] = b_b[src]; }
}

// ---------------- K3: attention scores + masked softmax ----------------
__global__ __launch_bounds__(256) void attn_alpha(
    const float* __restrict__ x, const float* __restrict__ tword,
    const float* __restrict__ W_h, const float* __restrict__ b_tanh,
    const int* __restrict__ xlen, float* __restrict__ alpha) {
  int b = blockIdx.x, tid = threadIdx.x;
  int lane = tid & 63, wave = tid >> 6;
  __shared__ float wred[4];
  __shared__ float uvals[LL];
  const float* tw = tword + (size_t)b * 5 * DD;
  float acc = 0.f;
  for (int i = tid; i < 5 * DD; i += 256) acc += tw[i] * W_h[DD + (i & (DD - 1))];
  #pragma unroll
  for (int off = 32; off; off >>= 1) acc += __shfl_down(acc, off);
  if (lane == 0) wred[wave] = acc;
  __syncthreads();
  float twdot = (wred[0] + wred[1] + wred[2] + wred[3]) * 0.2f;
  int len = xlen[b];
  const float* xb = x + (size_t)b * LL * DD;
  for (int l = wave; l < LL; l += 4) {
    float s = 0.f;
    if (l < len) {
      const float* xr = xb + (size_t)l * DD;
      for (int k = lane * 4; k < DD; k += 256) {
        float4 xv = *(const float4*)(xr + k);
        float4 wv = *(const float4*)(W_h + k);
        s += xv.x * wv.x + xv.y * wv.y + xv.z * wv.z + xv.w * wv.w;
      }
      #pragma unroll
      for (int off = 32; off; off >>= 1) s += __shfl_down(s, off);
    }
    if (lane == 0) uvals[l] = (l < len) ? (s + twdot + b_tanh[l]) : -1000000.0f;
  }
  __syncthreads();
  if (wave == 0) {
    float u0 = uvals[lane], u1 = uvals[lane + 64];
    float m = fmaxf(u0, u1);
    #pragma unroll
    for (int off = 32; off; off >>= 1) m = fmaxf(m, __shfl_down(m, off));
    m = __shfl(m, 0);
    float e0 = __expf(u0 - m), e1 = __expf(u1 - m);
    float ssum = e0 + e1;
    #pragma unroll
    for (int off = 32; off; off >>= 1) ssum += __shfl_down(ssum, off);
    ssum = __shfl(ssum, 0);
    alpha[(size_t)b * LL + lane] = e0 / ssum;
    alpha[(size_t)b * LL + lane + 64] = e1 / ssum;
  }
}

// ---------------- K4: big input-projection GEMM ----------------
__global__ __launch_bounds__(256) void gemm_bt(
    const u16* __restrict__ A, const u16* __restrict__ Bw, u16* __restrict__ C) {
  __shared__ u16 At[128 * 64];
  __shared__ u16 Bt[128 * 64];
  const int tid = threadIdx.x;
  const int lane = tid & 63, wave = tid >> 6;
  const int m0 = blockIdx.y * 128, n0 = blockIdx.x * 128;
  const int wm = (wave >> 1) * 64, wn = (wave & 1) * 64;
  const int l15 = lane & 15, quad = lane >> 4;
  f32x4 acc[4][4] = {};
  const int rs = tid >> 3;
  const int slot = tid & 7;
  for (int kt = 0; kt < 16; ++kt) {
    __syncthreads();
    #pragma unroll
    for (int cc = 0; cc < 4; ++cc) {
      int row = cc * 32 + rs;
      int kseg = slot ^ (row & 7);
      const u16* ga = A + (size_t)(m0 + row) * DD + kt * 64 + kseg * 8;
      const u16* gb = Bw + (size_t)(n0 + row) * DD + kt * 64 + kseg * 8;
      load_lds16(ga, (char*)At + cc * 4096 + tid * 16);
      load_lds16(gb, (char*)Bt + cc * 4096 + tid * 16);
    }
    __syncthreads();
    #pragma unroll
    for (int ks = 0; ks < 2; ++ks) {
      bf16x8 av[4], bv[4];
      int kq = ks * 4 + quad;
      #pragma unroll
      for (int i = 0; i < 4; ++i) {
        int row = wm + i * 16 + l15;
        av[i] = *(const bf16x8*)(At + row * 64 + (kq ^ (row & 7)) * 8);
      }
      #pragma unroll
      for (int j = 0; j < 4; ++j) {
        int row = wn + j * 16 + l15;
        bv[j] = *(const bf16x8*)(Bt + row * 64 + (kq ^ (row & 7)) * 8);
      }
      #pragma unroll
      for (int i = 0; i < 4; ++i)
        #pragma unroll
        for (int j = 0; j < 4; ++j)
          acc[i][j] = __builtin_amdgcn_mfma_f32_16x16x32_bf16(av[i], bv[j], acc[i][j], 0, 0, 0);
    }
  }
  #pragma unroll
  for (int i = 0; i < 4; ++i) {
    #pragma unroll
    for (int r = 0; r < 4; ++r) {
      size_t row = (size_t)(m0 + wm + i * 16 + quad * 4 + r);
      u16* crow = C + row * NN + n0 + wn + l15;
      #pragma unroll
      for (int j = 0; j < 4; ++j) crow[j * 16] = f2bf(acc[i][j][r]);
    }
  }
}

// ---------------- K5: persistent recurrence, XCD-local group barriers ------
// 256 blocks; group = bid&15 (16 members, bid>>4 = ncol). Under round-robin
// bid%8 XCD dispatch, all members of a group share one XCD/L2 -> exchange h
// through local L2 with NO cache-maintenance fences: stores drain via the
// __syncthreads vmcnt(0); loads use relaxed agent-scope 8B atomics (sc0 =
// L1 bypass). Mapping is verified at runtime via HW_REG_XCC_ID; if a group
// spans XCDs it falls back to full agent release/acquire fences (correct
// under any dispatch mapping, per G16).
__global__ __launch_bounds__(256, 1) void lstm_persist(
    const u16* __restrict__ P, const u16* __restrict__ Whh_p,
    const float* __restrict__ bias_p, const float* __restrict__ alpha,
    const int* __restrict__ xlen, u16* __restrict__ hfrag,
    float* __restrict__ ctx, int* __restrict__ bar, unsigned* __restrict__ xmask) {
  __shared__ u16 Wl[128 * 512];        // XOR-swizzled k-segments
  __shared__ float gbuf[32][132];
  __shared__ float biasl[128];
  __shared__ int xl[32];
  __shared__ unsigned same_sh;
  const int tid = threadIdx.x;
  const int lane = tid & 63, wave = tid >> 6;
  const int l15 = lane & 15, quad = lane >> 4;
  const int bid = blockIdx.x;
  const int gid = bid & 15;            // group: members are bid = gid + 16*k
  const int ncol = bid >> 4;
  const int dir = gid >> 3, btile = gid & 7;

  // one-time: W chunk -> LDS (row = local perm col 0..127, K=512), swizzled
  {
    const u16* Wb = Whh_p + ((size_t)dir * GG + ncol * 128) * HH;
    for (int idx = tid; idx < 128 * 64; idx += 256) {
      int row = idx >> 6, seg = idx & 63;
      int sseg = seg ^ (row & 7);
      *(uint4*)&Wl[row * 512 + sseg * 8] = *(const uint4*)(Wb + (size_t)row * HH + seg * 8);
    }
  }
  if (tid < 128) biasl[tid] = bias_p[(size_t)dir * GG + ncol * 128 + tid];
  if (tid < 32) xl[tid] = xlen[btile * 32 + tid];

  // ---- XCD-homogeneity probe + setup barrier (heavy, one-time) ----
  unsigned xcc;
  asm volatile("s_getreg_b32 %0, hwreg(HW_REG_XCC_ID)" : "=s"(xcc));
  if (tid == 0) {
    __hip_atomic_fetch_or(&xmask[gid], 1u << (xcc & 31), __ATOMIC_RELAXED,
                          __HIP_MEMORY_SCOPE_AGENT);
    __builtin_amdgcn_fence(__ATOMIC_RELEASE, "agent");
    int* c = bar + ((size_t)gid * (LL + 1) + LL) * 32;
    __hip_atomic_fetch_add(c, 1, __ATOMIC_RELAXED, __HIP_MEMORY_SCOPE_AGENT);
    while (__hip_atomic_load(c, __ATOMIC_RELAXED, __HIP_MEMORY_SCOPE_AGENT) < 16)
      __builtin_amdgcn_s_sleep(1);
    __builtin_amdgcn_fence(__ATOMIC_ACQUIRE, "agent");
    same_sh = (__popc(__hip_atomic_load(&xmask[gid], __ATOMIC_RELAXED,
                                        __HIP_MEMORY_SCOPE_AGENT)) == 1) ? 1u : 0u;
  }
  __syncthreads();
  const bool same_xcd = (same_sh != 0);

  // gate-phase ownership: thread = (b_local, jb) -> 4 hidden units
  const int b_local = tid >> 3, jb = tid & 7;
  const int b_glob = btile * 32 + b_local;
  const int jg0 = ncol * 32 + jb * 4;
  const size_t hslot = ((size_t)(dir * 64 + (jg0 >> 3)) * 256 + b_glob) * 8 + (jg0 & 7);
  const int len = xl[b_local];

  float creg[4] = {0.f, 0.f, 0.f, 0.f};
  float ctxa[4] = {0.f, 0.f, 0.f, 0.f};
  u16 hv[4] = {0, 0, 0, 0};            // carried h (registers)

  // MFMA-phase decode: wave -> 16-batch subtile, 64-col half
  const int bt = wave >> 1, ch = wave & 1;
  const int b0 = btile * 32 + bt * 16;

  // prefetch P/alpha for step 0
  const u16* Pbase = P + (size_t)b_glob * LL * NN + (size_t)dir * GG + ncol * 128 + jb * 16;
  int t0 = dir ? (len - 1) : 0;
  t0 = min(max(t0, 0), LL - 1);
  uint4 pa = *(const uint4*)(Pbase + (size_t)t0 * NN);
  uint4 pb = *(const uint4*)(Pbase + (size_t)t0 * NN + 8);
  float al = alpha[(size_t)b_glob * LL + t0];

  const size_t HBUF = (size_t)2 * 64 * 256 * 8;  // u16 elems per h buffer
  for (int s = 0; s < LL; ++s) {
    const u16* hc = hfrag + (size_t)(s & 1) * HBUF;   // buf0 pre-zeroed
    u16* hx = hfrag + (size_t)((s + 1) & 1) * HBUF;

    // ---- GEMM: (16 batches) x (64 cols) x K=512 per wave ----
    // L1-bypassing 8B atomic loads (sc0): coherent through local L2.
    bf16x8 av[16];
    #pragma unroll
    for (int ks = 0; ks < 16; ++ks) {
      const ull* ap = (const ull*)(hc + ((size_t)(dir * 64 + ks * 4 + quad) * 256 + b0 + l15) * 8);
      union { ull q[2]; bf16x8 v; } u;
      u.q[0] = __hip_atomic_load(ap, __ATOMIC_RELAXED, __HIP_MEMORY_SCOPE_AGENT);
      u.q[1] = __hip_atomic_load(ap + 1, __ATOMIC_RELAXED, __HIP_MEMORY_SCOPE_AGENT);
      av[ks] = u.v;
    }
    f32x4 acc[4] = {};
    #pragma unroll
    for (int ks = 0; ks < 16; ++ks) {
      #pragma unroll
      for (int nt = 0; nt < 4; ++nt) {
        int r = ch * 64 + nt * 16 + l15;
        bf16x8 bv = *(const bf16x8*)&Wl[r * 512 + ((ks * 4 + quad) ^ (r & 7)) * 8];
        acc[nt] = __builtin_amdgcn_mfma_f32_16x16x32_bf16(av[ks], bv, acc[nt], 0, 0, 0);
      }
    }
    #pragma unroll
    for (int nt = 0; nt < 4; ++nt)
      #pragma unroll
      for (int r = 0; r < 4; ++r)
        gbuf[bt * 16 + quad * 4 + r][ch * 64 + nt * 16 + l15] = acc[nt][r];
    __syncthreads();

    // ---- gates ----
    const bool valid = s < len;
    unsigned pw[8] = {pa.x, pa.y, pa.z, pa.w, pb.x, pb.y, pb.z, pb.w};
    #pragma unroll
    for (int u = 0; u < 4; ++u) {
      float4 gv = *(const float4*)&gbuf[b_local][jb * 16 + u * 4];
      float4 bb = *(const float4*)&biasl[jb * 16 + u * 4];
      float gi = gv.x + __uint_as_float(pw[u * 2] << 16) + bb.x;
      float gf = gv.y + __uint_as_float(pw[u * 2] & 0xffff0000u) + bb.y;
      float gz = gv.z + __uint_as_float(pw[u * 2 + 1] << 16) + bb.z;
      float go = gv.w + __uint_as_float(pw[u * 2 + 1] & 0xffff0000u) + bb.w;
      float ig = sigm(gi), fg = sigm(gf), zg = tanh_fast(gz), og = sigm(go);
      float cn = fg * creg[u] + ig * zg;
      float hn = og * tanh_fast(cn);
      if (valid) {
        creg[u] = cn;
        ctxa[u] += al * hn;
        hv[u] = f2bf(hn);
      }
    }
    *(ushort4*)&hx[hslot] = make_ushort4(hv[0], hv[1], hv[2], hv[3]);

    // ---- prefetch P/alpha for step s+1 (overlaps barrier) ----
    int tn = dir ? (len - 2 - s) : (s + 1);
    tn = min(max(tn, 0), LL - 1);
    uint4 npa = *(const uint4*)(Pbase + (size_t)tn * NN);
    uint4 npb = *(const uint4*)(Pbase + (size_t)tn * NN + 8);
    float nal = alpha[(size_t)b_glob * LL + tn];

    // ---- group barrier (skip after last step) ----
    if (s < LL - 1) {
      __syncthreads();   // all waves' h stores acked (vmcnt 0); gbuf WAR safe
      if (tid == 0) {
        int* c = bar + ((size_t)gid * (LL + 1) + s) * 32;   // one-shot counter
        if (same_xcd) {
          // same-L2 fast path: no cache maintenance
          __hip_atomic_fetch_add(c, 1, __ATOMIC_RELAXED, __HIP_MEMORY_SCOPE_AGENT);
          while (__hip_atomic_load(c, __ATOMIC_RELAXED, __HIP_MEMORY_SCOPE_AGENT) < 16)
            ;
          __builtin_amdgcn_fence(__ATOMIC_ACQUIRE, "workgroup");  // order only
        } else {
          __builtin_amdgcn_fence(__ATOMIC_RELEASE, "agent");
          __hip_atomic_fetch_add(c, 1, __ATOMIC_RELAXED, __HIP_MEMORY_SCOPE_AGENT);
          while (__hip_atomic_load(c, __ATOMIC_RELAXED, __HIP_MEMORY_SCOPE_AGENT) < 16)
            __builtin_amdgcn_s_sleep(1);
          __builtin_amdgcn_fence(__ATOMIC_ACQUIRE, "agent");
        }
      }
      __syncthreads();
    }
    pa = npa; pb = npb; al = nal;
  }

  #pragma unroll
  for (int u = 0; u < 4; ++u)
    ctx[(size_t)b_glob * (2 * HH) + dir * HH + jg0 + u] = ctxa[u];
}

// ---------------- K6: head ----------------
__global__ __launch_bounds__(256) void head(
    const float* __restrict__ ctx, const float* __restrict__ W_lin,
    const float* __restrict__ b_lin, const float* __restrict__ W_out,
    const float* __restrict__ b_out, float* __restrict__ out) {
  int b = blockIdx.x, tid = threadIdx.x;
  __shared__ float cbuf[2 * HH];
  __shared__ float lbuf[LINN];
  *(float4*)&cbuf[tid * 4] = *(const float4*)&ctx[(size_t)b * (2 * HH) + tid * 4];
  __syncthreads();
  #pragma unroll
  for (int rr = 0; rr < 2; ++rr) {
    int row = tid + rr * 256;
    const float* wr = W_lin + (size_t)row * (2 * HH);
    float s = 0.f;
    for (int k = 0; k < 2 * HH; k += 4) {
      float4 wv = *(const float4*)(wr + k);
      float4 cv = *(const float4*)(cbuf + k);
      s += wv.x * cv.x + wv.y * cv.y + wv.z * cv.z + wv.w * cv.w;
    }
    lbuf[row] = fmaxf(s + b_lin[row], 0.0f);
  }
  __syncthreads();
  int lane = tid & 63, wave = tid >> 6;
  if (wave < 3) {
    const float* wo = W_out + (size_t)wave * LINN;
    float s = 0.f;
    for (int k = lane; k < LINN; k += 64) s += lbuf[k] * wo[k];
    #pragma unroll
    for (int off = 32; off; off >>= 1) s += __shfl_down(s, off);
    if (lane == 0) out[(size_t)b * 3 + wave] = s + b_out[wave];
  }
}

extern "C" void kernel_launch(void* const* d_in, const int* in_sizes, int n_in,
                              void* d_out, int out_size, void* d_ws, size_t ws_size,
                              hipStream_t stream) {
  (void)in_sizes; (void)n_in; (void)out_size; (void)ws_size;
  const float* x      = (const float*)d_in[0];
  const int*   xlen   = (const int*)d_in[1];
  const float* tword  = (const float*)d_in[3];
  const float* Wih_f  = (const float*)d_in[5];
  const float* Whh_f  = (const float*)d_in[6];
  const float* b_f    = (const float*)d_in[7];
  const float* Wih_b  = (const float*)d_in[8];
  const float* Whh_b  = (const float*)d_in[9];
  const float* b_b    = (const float*)d_in[10];
  const float* W_h    = (const float*)d_in[11];
  const float* b_tanh = (const float*)d_in[12];
  const float* W_lin  = (const float*)d_in[13];
  const float* b_lin  = (const float*)d_in[14];
  const float* W_out  = (const float*)d_in[15];
  const float* b_out  = (const float*)d_in[16];
  float* out = (float*)d_out;

  char* w = (char*)d_ws;
  u16* xe_bf = (u16*)w;      w += (size_t)NB * LL * DD * 2;     // 64 MB
  u16* Pbuf  = (u16*)w;      w += (size_t)NB * LL * NN * 2;     // 256 MB
  u16* Wih_p = (u16*)w;      w += (size_t)2 * GG * DD * 2;      // 8 MB
  u16* Whh_p = (u16*)w;      w += (size_t)2 * GG * HH * 2;      // 4 MB
  float* bias_p = (float*)w; w += (size_t)2 * GG * 4;
  float* alphaW = (float*)w; w += (size_t)NB * LL * 4;
  u16* hfrag = (u16*)w;      w += (size_t)2 * 2 * 64 * 256 * 8 * 2;  // 1 MB
  float* ctxb = (float*)w;   w += (size_t)NB * 2 * HH * 4;
  int* barW  = (int*)w;      w += (size_t)16 * (LL + 1) * 32 * 4;  // one-shot counters
  unsigned* xmaskW = (unsigned*)w; w += 16 * 4;

  // buffer 0 of hfrag must be zero (h_0 = 0); counters/masks start at 0
  hipMemsetAsync(hfrag, 0, (size_t)2 * 64 * 256 * 8 * 2, stream);
  hipMemsetAsync(barW, 0, (size_t)16 * (LL + 1) * 32 * 4, stream);
  hipMemsetAsync(xmaskW, 0, 16 * 4, stream);

  conv_bf16<<<16384, 256, 0, stream>>>(x, xe_bf);
  prep_weights<<<8192, 256, 0, stream>>>(Wih_f, Whh_f, b_f, Wih_b, Whh_b, b_b,
                                         Wih_p, Whh_p, bias_p);
  attn_alpha<<<256, 256, 0, stream>>>(x, tword, W_h, b_tanh, xlen, alphaW);
  gemm_bt<<<dim3(32, 256), 256, 0, stream>>>(xe_bf, Wih_p, Pbuf);

  {
    const u16* Pc = Pbuf;
    const u16* Wc = Whh_p;
    const float* bc = bias_p;
    const float* ac = alphaW;
    const int* lc = xlen;
    u16* hc = hfrag;
    float* cc = ctxb;
    int* brc = barW;
    unsigned* xm = xmaskW;
    void* kargs[] = {&Pc, &Wc, &bc, &ac, &lc, &hc, &cc, &brc, &xm};
    hipLaunchCooperativeKernel((const void*)lstm_persist, dim3(256), dim3(256),
                               kargs, 0, stream);
  }

  head<<<256, 256, 0, stream>>>(ctxb, W_lin, b_lin, W_out, b_out, out);
}

// Round 5
// 1258.761 us; speedup vs baseline: 4.1353x; 1.0380x over previous
//
#include <hip/hip_runtime.h>
#include <cstdint>
#include <cstddef>

typedef unsigned short u16;
typedef unsigned long long ull;
typedef __attribute__((ext_vector_type(8))) short bf16x8;
typedef __attribute__((ext_vector_type(4))) float f32x4;

#define NB 256
#define LL 128
#define DD 1024
#define HH 512
#define GG 2048   // 4H
#define NN 4096   // 2*GG
#define LINN 512

__device__ __forceinline__ u16 f2bf(float f) {
  unsigned u = __float_as_uint(f);
  u += 0x7fffu + ((u >> 16) & 1u);
  return (u16)(u >> 16);
}
__device__ __forceinline__ float sigm(float x) { return 1.0f / (1.0f + __expf(-x)); }
__device__ __forceinline__ float tanh_fast(float x) {
  float a = fabsf(x);
  float e = __expf(-2.0f * a);
  float t = (1.0f - e) / (1.0f + e);
  return copysignf(t, x);
}
__device__ __forceinline__ void load_lds16(const void* g, void* l) {
  __builtin_amdgcn_global_load_lds(
      (const __attribute__((address_space(1))) void*)g,
      (__attribute__((address_space(3))) void*)l, 16, 0, 0);
}

// ---------------- K1: fp32 -> bf16 convert of x ----------------
__global__ __launch_bounds__(256) void conv_bf16(const float* __restrict__ in,
                                                 u16* __restrict__ out) {
  size_t i = ((size_t)blockIdx.x * 256 + threadIdx.x) * 8;
  float4 a = *(const float4*)(in + i);
  float4 b = *(const float4*)(in + i + 4);
  uint4 v;
  v.x = (unsigned)f2bf(a.x) | ((unsigned)f2bf(a.y) << 16);
  v.y = (unsigned)f2bf(a.z) | ((unsigned)f2bf(a.w) << 16);
  v.z = (unsigned)f2bf(b.x) | ((unsigned)f2bf(b.y) << 16);
  v.w = (unsigned)f2bf(b.z) | ((unsigned)f2bf(b.w) << 16);
  *(uint4*)(out + i) = v;
}

// ---------------- K2: permute+convert weights ----------------
// permuted row p = 4*j + gate  <-  original row gate*512 + j
__global__ __launch_bounds__(256) void prep_weights(
    const float* __restrict__ Wih_f, const float* __restrict__ Whh_f, const float* __restrict__ b_f,
    const float* __restrict__ Wih_b, const float* __restrict__ Whh_b, const float* __restrict__ b_b,
    u16* __restrict__ Wih_p, u16* __restrict__ Whh_p, float* __restrict__ bias_p) {
  int idx = blockIdx.x * 256 + threadIdx.x;   // 0 .. 2048*1024-1
  int p = idx >> 10, k = idx & 1023;
  int src = ((p & 3) << 9) | (p >> 2);
  Wih_p[(size_t)p * DD + k] = f2bf(Wih_f[(size_t)src * DD + k]);
  Wih_p[(size_t)GG * DD + (size_t)p * DD + k] = f2bf(Wih_b[(size_t)src * DD + k]);
  if (k < HH) {
    Whh_p[(size_t)p * HH + k] = f2bf(Whh_f[(size_t)src * HH + k]);
    Whh_p[(size_t)GG * HH + (size_t)p * HH + k] = f2bf(Whh_b[(size_t)src * HH + k]);
  }
  if (k == 0) { bias_p[p] = b_f[src]; bias_p[GG + p] = b_b[src]; }
}

// ---------------- K3: attention scores + masked softmax ----------------
__global__ __launch_bounds__(256) void attn_alpha(
    const float* __restrict__ x, const float* __restrict__ tword,
    const float* __restrict__ W_h, const float* __restrict__ b_tanh,
    const int* __restrict__ xlen, float* __restrict__ alpha) {
  int b = blockIdx.x, tid = threadIdx.x;
  int lane = tid & 63, wave = tid >> 6;
  __shared__ float wred[4];
  __shared__ float uvals[LL];
  const float* tw = tword + (size_t)b * 5 * DD;
  float acc = 0.f;
  for (int i = tid; i < 5 * DD; i += 256) acc += tw[i] * W_h[DD + (i & (DD - 1))];
  #pragma unroll
  for (int off = 32; off; off >>= 1) acc += __shfl_down(acc, off);
  if (lane == 0) wred[wave] = acc;
  __syncthreads();
  float twdot = (wred[0] + wred[1] + wred[2] + wred[3]) * 0.2f;
  int len = xlen[b];
  const float* xb = x + (size_t)b * LL * DD;
  for (int l = wave; l < LL; l += 4) {
    float s = 0.f;
    if (l < len) {
      const float* xr = xb + (size_t)l * DD;
      for (int k = lane * 4; k < DD; k += 256) {
        float4 xv = *(const float4*)(xr + k);
        float4 wv = *(const float4*)(W_h + k);
        s += xv.x * wv.x + xv.y * wv.y + xv.z * wv.z + xv.w * wv.w;
      }
      #pragma unroll
      for (int off = 32; off; off >>= 1) s += __shfl_down(s, off);
    }
    if (lane == 0) uvals[l] = (l < len) ? (s + twdot + b_tanh[l]) : -1000000.0f;
  }
  __syncthreads();
  if (wave == 0) {
    float u0 = uvals[lane], u1 = uvals[lane + 64];
    float m = fmaxf(u0, u1);
    #pragma unroll
    for (int off = 32; off; off >>= 1) m = fmaxf(m, __shfl_down(m, off));
    m = __shfl(m, 0);
    float e0 = __expf(u0 - m), e1 = __expf(u1 - m);
    float ssum = e0 + e1;
    #pragma unroll
    for (int off = 32; off; off >>= 1) ssum += __shfl_down(ssum, off);
    ssum = __shfl(ssum, 0);
    alpha[(size_t)b * LL + lane] = e0 / ssum;
    alpha[(size_t)b * LL + lane + 64] = e1 / ssum;
  }
}

// ---------------- K4: big input-projection GEMM ----------------
__global__ __launch_bounds__(256) void gemm_bt(
    const u16* __restrict__ A, const u16* __restrict__ Bw, u16* __restrict__ C) {
  __shared__ u16 At[128 * 64];
  __shared__ u16 Bt[128 * 64];
  const int tid = threadIdx.x;
  const int lane = tid & 63, wave = tid >> 6;
  const int m0 = blockIdx.y * 128, n0 = blockIdx.x * 128;
  const int wm = (wave >> 1) * 64, wn = (wave & 1) * 64;
  const int l15 = lane & 15, quad = lane >> 4;
  f32x4 acc[4][4] = {};
  const int rs = tid >> 3;
  const int slot = tid & 7;
  for (int kt = 0; kt < 16; ++kt) {
    __syncthreads();
    #pragma unroll
    for (int cc = 0; cc < 4; ++cc) {
      int row = cc * 32 + rs;
      int kseg = slot ^ (row & 7);
      const u16* ga = A + (size_t)(m0 + row) * DD + kt * 64 + kseg * 8;
      const u16* gb = Bw + (size_t)(n0 + row) * DD + kt * 64 + kseg * 8;
      load_lds16(ga, (char*)At + cc * 4096 + tid * 16);
      load_lds16(gb, (char*)Bt + cc * 4096 + tid * 16);
    }
    __syncthreads();
    #pragma unroll
    for (int ks = 0; ks < 2; ++ks) {
      bf16x8 av[4], bv[4];
      int kq = ks * 4 + quad;
      #pragma unroll
      for (int i = 0; i < 4; ++i) {
        int row = wm + i * 16 + l15;
        av[i] = *(const bf16x8*)(At + row * 64 + (kq ^ (row & 7)) * 8);
      }
      #pragma unroll
      for (int j = 0; j < 4; ++j) {
        int row = wn + j * 16 + l15;
        bv[j] = *(const bf16x8*)(Bt + row * 64 + (kq ^ (row & 7)) * 8);
      }
      #pragma unroll
      for (int i = 0; i < 4; ++i)
        #pragma unroll
        for (int j = 0; j < 4; ++j)
          acc[i][j] = __builtin_amdgcn_mfma_f32_16x16x32_bf16(av[i], bv[j], acc[i][j], 0, 0, 0);
    }
  }
  #pragma unroll
  for (int i = 0; i < 4; ++i) {
    #pragma unroll
    for (int r = 0; r < 4; ++r) {
      size_t row = (size_t)(m0 + wm + i * 16 + quad * 4 + r);
      u16* crow = C + row * NN + n0 + wn + l15;
      #pragma unroll
      for (int j = 0; j < 4; ++j) crow[j * 16] = f2bf(acc[i][j][r]);
    }
  }
}

// ---------------- K5: persistent recurrence -------------------------------
// 256 blocks; group = bid&15 -> (dir,btile); member ncol = bid>>4 (16 per
// group, all on one XCD under round-robin dispatch -> shared L2).
// This round: W slice lives in 128 VGPRs per wave (no W LDS reads); h is
// staged to a 32KB LDS tile per step; barrier = one-shot FLAG per
// (group,step,member): plain sc0 store + relaxed agent-load poll, all
// XCD-L2-local (no MALL atomics, no cache-maintenance fences). Cross-XCD
// fallback keeps the round-3 heavy fence barrier.
__global__ __launch_bounds__(256, 1) void lstm_persist(
    const u16* __restrict__ P, const u16* __restrict__ Whh_p,
    const float* __restrict__ bias_p, const float* __restrict__ alpha,
    const int* __restrict__ xlen, u16* __restrict__ hfrag,
    float* __restrict__ ctx, int* __restrict__ bar,
    unsigned* __restrict__ xmask, int* __restrict__ flags) {
  __shared__ u16 Hs[64 * 32 * 8];      // h-stage: [kchunk 0..63][b_local 0..31][8] = 32KB
  __shared__ float gbuf[32][132];
  __shared__ int xl[32];
  __shared__ unsigned same_sh;
  const int tid = threadIdx.x;
  const int lane = tid & 63, wave = tid >> 6;
  const int l15 = lane & 15, quad = lane >> 4;
  const int bid = blockIdx.x;
  const int gid = bid & 15;            // group: members are bid = gid + 16*k
  const int ncol = bid >> 4;
  const int dir = gid >> 3, btile = gid & 7;

  // one-time: W slice -> registers. wave covers block-local cols wave*32..+31
  bf16x8 bw[2][16];
  {
    const u16* Wb = Whh_p + ((size_t)dir * GG + ncol * 128 + wave * 32) * HH;
    #pragma unroll
    for (int nt = 0; nt < 2; ++nt)
      #pragma unroll
      for (int ks = 0; ks < 16; ++ks)
        bw[nt][ks] = *(const bf16x8*)(Wb + (size_t)(nt * 16 + l15) * HH + ks * 32 + quad * 8);
  }
  if (tid < 32) xl[tid] = xlen[btile * 32 + tid];

  // ---- XCD-homogeneity probe + setup barrier (heavy, one-time) ----
  unsigned xcc;
  asm volatile("s_getreg_b32 %0, hwreg(HW_REG_XCC_ID)" : "=s"(xcc));
  if (tid == 0) {
    __hip_atomic_fetch_or(&xmask[gid], 1u << (xcc & 31), __ATOMIC_RELAXED,
                          __HIP_MEMORY_SCOPE_AGENT);
    __builtin_amdgcn_fence(__ATOMIC_RELEASE, "agent");
    int* c = bar + ((size_t)gid * (LL + 1) + LL) * 32;
    __hip_atomic_fetch_add(c, 1, __ATOMIC_RELAXED, __HIP_MEMORY_SCOPE_AGENT);
    while (__hip_atomic_load(c, __ATOMIC_RELAXED, __HIP_MEMORY_SCOPE_AGENT) < 16)
      __builtin_amdgcn_s_sleep(1);
    __builtin_amdgcn_fence(__ATOMIC_ACQUIRE, "agent");
    same_sh = (__popc(__hip_atomic_load(&xmask[gid], __ATOMIC_RELAXED,
                                        __HIP_MEMORY_SCOPE_AGENT)) == 1) ? 1u : 0u;
  }
  __syncthreads();
  const bool same_xcd = (same_sh != 0);

  // gate-phase ownership: thread = (b_local, jb) -> 4 hidden units
  const int b_local = tid >> 3, jb = tid & 7;
  const int b_glob = btile * 32 + b_local;
  const int jg0 = ncol * 32 + jb * 4;
  const size_t hslot = ((size_t)(dir * 64 + (jg0 >> 3)) * 256 + b_glob) * 8 + (jg0 & 7);
  const int len = xl[b_local];

  // bias in registers (was LDS -> bank conflicts)
  float4 bb[4];
  #pragma unroll
  for (int u = 0; u < 4; ++u)
    bb[u] = *(const float4*)(bias_p + (size_t)dir * GG + ncol * 128 + jb * 16 + u * 4);

  float creg[4] = {0.f, 0.f, 0.f, 0.f};
  float ctxa[4] = {0.f, 0.f, 0.f, 0.f};
  u16 hv[4] = {0, 0, 0, 0};            // carried h (registers)

  // prefetch P/alpha for step 0
  const u16* Pbase = P + (size_t)b_glob * LL * NN + (size_t)dir * GG + ncol * 128 + jb * 16;
  int t0 = dir ? (len - 1) : 0;
  t0 = min(max(t0, 0), LL - 1);
  uint4 pa = *(const uint4*)(Pbase + (size_t)t0 * NN);
  uint4 pb = *(const uint4*)(Pbase + (size_t)t0 * NN + 8);
  float al = alpha[(size_t)b_glob * LL + t0];

  const size_t HBUF = (size_t)2 * 64 * 256 * 8;  // u16 elems per h buffer
  for (int s = 0; s < LL; ++s) {
    const u16* hc = hfrag + (size_t)(s & 1) * HBUF;   // buf0 pre-zeroed
    u16* hx = hfrag + (size_t)((s + 1) & 1) * HBUF;

    // ---- stage h -> LDS (L1-bypassing 8B atomic loads, XCD-L2 coherent) --
    #pragma unroll
    for (int i = 0; i < 8; ++i) {
      int j = i * 256 + tid;            // chunk: kc = j>>5, bl = j&31
      const ull* ap = (const ull*)(hc + ((size_t)(dir * 64 + (j >> 5)) * 256 + btile * 32 + (j & 31)) * 8);
      union { ull q[2]; uint4 v; } un;
      un.q[0] = __hip_atomic_load(ap, __ATOMIC_RELAXED, __HIP_MEMORY_SCOPE_AGENT);
      un.q[1] = __hip_atomic_load(ap + 1, __ATOMIC_RELAXED, __HIP_MEMORY_SCOPE_AGENT);
      *(uint4*)&Hs[(size_t)j * 8] = un.v;
    }
    __syncthreads();

    // ---- GEMM: all 32 batches x 32 cols x K=512 per wave, W from regs ----
    f32x4 acc[2][2] = {};
    #pragma unroll
    for (int ks = 0; ks < 16; ++ks) {
      bf16x8 a0 = *(const bf16x8*)&Hs[(size_t)((ks * 4 + quad) * 32 + l15) * 8];
      bf16x8 a1 = *(const bf16x8*)&Hs[(size_t)((ks * 4 + quad) * 32 + 16 + l15) * 8];
      acc[0][0] = __builtin_amdgcn_mfma_f32_16x16x32_bf16(a0, bw[0][ks], acc[0][0], 0, 0, 0);
      acc[0][1] = __builtin_amdgcn_mfma_f32_16x16x32_bf16(a0, bw[1][ks], acc[0][1], 0, 0, 0);
      acc[1][0] = __builtin_amdgcn_mfma_f32_16x16x32_bf16(a1, bw[0][ks], acc[1][0], 0, 0, 0);
      acc[1][1] = __builtin_amdgcn_mfma_f32_16x16x32_bf16(a1, bw[1][ks], acc[1][1], 0, 0, 0);
    }
    // epilogue with column swizzle: value for col c goes to chunk (u+(jb>>1))&3
    #pragma unroll
    for (int mt = 0; mt < 2; ++mt)
      #pragma unroll
      for (int nt = 0; nt < 2; ++nt) {
        int col = wave * 32 + nt * 16 + l15;
        int jbw = col >> 4;                       // wave-uniform
        int swz = jbw * 16 + ((((col >> 2) & 3) + (jbw >> 1)) & 3) * 4 + (col & 3);
        #pragma unroll
        for (int r = 0; r < 4; ++r)
          gbuf[mt * 16 + quad * 4 + r][swz] = acc[mt][nt][r];
      }
    __syncthreads();

    // ---- gates ----
    const bool valid = s < len;
    unsigned pw[8] = {pa.x, pa.y, pa.z, pa.w, pb.x, pb.y, pb.z, pb.w};
    #pragma unroll
    for (int u = 0; u < 4; ++u) {
      int cswz = jb * 16 + ((u + (jb >> 1)) & 3) * 4;
      float4 gv = *(const float4*)&gbuf[b_local][cswz];
      float gi = gv.x + __uint_as_float(pw[u * 2] << 16) + bb[u].x;
      float gf = gv.y + __uint_as_float(pw[u * 2] & 0xffff0000u) + bb[u].y;
      float gz = gv.z + __uint_as_float(pw[u * 2 + 1] << 16) + bb[u].z;
      float go = gv.w + __uint_as_float(pw[u * 2 + 1] & 0xffff0000u) + bb[u].w;
      float ig = sigm(gi), fg = sigm(gf), zg = tanh_fast(gz), og = sigm(go);
      float cn = fg * creg[u] + ig * zg;
      float hn = og * tanh_fast(cn);
      if (valid) {
        creg[u] = cn;
        ctxa[u] += al * hn;
        hv[u] = f2bf(hn);
      }
    }
    *(ushort4*)&hx[hslot] = make_ushort4(hv[0], hv[1], hv[2], hv[3]);

    // ---- prefetch P/alpha for step s+1 (overlaps barrier) ----
    int tn = dir ? (len - 2 - s) : (s + 1);
    tn = min(max(tn, 0), LL - 1);
    uint4 npa = *(const uint4*)(Pbase + (size_t)tn * NN);
    uint4 npb = *(const uint4*)(Pbase + (size_t)tn * NN + 8);
    float nal = alpha[(size_t)b_glob * LL + tn];

    // ---- group barrier (skip after last step) ----
    if (s < LL - 1) {
      __syncthreads();   // drains vmcnt: all h stores acked in L2
      if (same_xcd) {
        int* f = flags + ((size_t)gid * LL + s) * 16;
        if (tid == 0)
          __hip_atomic_store(&f[ncol], 1, __ATOMIC_RELAXED, __HIP_MEMORY_SCOPE_AGENT);
        if (wave == 0 && lane < 16) {
          while (__hip_atomic_load(&f[lane], __ATOMIC_RELAXED, __HIP_MEMORY_SCOPE_AGENT) == 0)
            ;
        }
        __builtin_amdgcn_fence(__ATOMIC_ACQUIRE, "workgroup");  // order only
      } else if (tid == 0) {
        int* c = bar + ((size_t)gid * (LL + 1) + s) * 32;
        __builtin_amdgcn_fence(__ATOMIC_RELEASE, "agent");
        __hip_atomic_fetch_add(c, 1, __ATOMIC_RELAXED, __HIP_MEMORY_SCOPE_AGENT);
        while (__hip_atomic_load(c, __ATOMIC_RELAXED, __HIP_MEMORY_SCOPE_AGENT) < 16)
          __builtin_amdgcn_s_sleep(1);
        __builtin_amdgcn_fence(__ATOMIC_ACQUIRE, "agent");
      }
      __syncthreads();
    }
    pa = npa; pb = npb; al = nal;
  }

  #pragma unroll
  for (int u = 0; u < 4; ++u)
    ctx[(size_t)b_glob * (2 * HH) + dir * HH + jg0 + u] = ctxa[u];
}

// ---------------- K6: head ----------------
__global__ __launch_bounds__(256) void head(
    const float* __restrict__ ctx, const float* __restrict__ W_lin,
    const float* __restrict__ b_lin, const float* __restrict__ W_out,
    const float* __restrict__ b_out, float* __restrict__ out) {
  int b = blockIdx.x, tid = threadIdx.x;
  __shared__ float cbuf[2 * HH];
  __shared__ float lbuf[LINN];
  *(float4*)&cbuf[tid * 4] = *(const float4*)&ctx[(size_t)b * (2 * HH) + tid * 4];
  __syncthreads();
  #pragma unroll
  for (int rr = 0; rr < 2; ++rr) {
    int row = tid + rr * 256;
    const float* wr = W_lin + (size_t)row * (2 * HH);
    float s = 0.f;
    for (int k = 0; k < 2 * HH; k += 4) {
      float4 wv = *(const float4*)(wr + k);
      float4 cv = *(const float4*)(cbuf + k);
      s += wv.x * cv.x + wv.y * cv.y + wv.z * cv.z + wv.w * cv.w;
    }
    lbuf[row] = fmaxf(s + b_lin[row], 0.0f);
  }
  __syncthreads();
  int lane = tid & 63, wave = tid >> 6;
  if (wave < 3) {
    const float* wo = W_out + (size_t)wave * LINN;
    float s = 0.f;
    for (int k = lane; k < LINN; k += 64) s += lbuf[k] * wo[k];
    #pragma unroll
    for (int off = 32; off; off >>= 1) s += __shfl_down(s, off);
    if (lane == 0) out[(size_t)b * 3 + wave] = s + b_out[wave];
  }
}

extern "C" void kernel_launch(void* const* d_in, const int* in_sizes, int n_in,
                              void* d_out, int out_size, void* d_ws, size_t ws_size,
                              hipStream_t stream) {
  (void)in_sizes; (void)n_in; (void)out_size; (void)ws_size;
  const float* x      = (const float*)d_in[0];
  const int*   xlen   = (const int*)d_in[1];
  const float* tword  = (const float*)d_in[3];
  const float* Wih_f  = (const float*)d_in[5];
  const float* Whh_f  = (const float*)d_in[6];
  const float* b_f    = (const float*)d_in[7];
  const float* Wih_b  = (const float*)d_in[8];
  const float* Whh_b  = (const float*)d_in[9];
  const float* b_b    = (const float*)d_in[10];
  const float* W_h    = (const float*)d_in[11];
  const float* b_tanh = (const float*)d_in[12];
  const float* W_lin  = (const float*)d_in[13];
  const float* b_lin  = (const float*)d_in[14];
  const float* W_out  = (const float*)d_in[15];
  const float* b_out  = (const float*)d_in[16];
  float* out = (float*)d_out;

  char* w = (char*)d_ws;
  u16* xe_bf = (u16*)w;      w += (size_t)NB * LL * DD * 2;     // 64 MB
  u16* Pbuf  = (u16*)w;      w += (size_t)NB * LL * NN * 2;     // 256 MB
  u16* Wih_p = (u16*)w;      w += (size_t)2 * GG * DD * 2;      // 8 MB
  u16* Whh_p = (u16*)w;      w += (size_t)2 * GG * HH * 2;      // 4 MB
  float* bias_p = (float*)w; w += (size_t)2 * GG * 4;
  float* alphaW = (float*)w; w += (size_t)NB * LL * 4;
  u16* hfrag = (u16*)w;      w += (size_t)2 * 2 * 64 * 256 * 8 * 2;  // 1 MB
  float* ctxb = (float*)w;   w += (size_t)NB * 2 * HH * 4;
  int* barW  = (int*)w;      w += (size_t)16 * (LL + 1) * 32 * 4;  // heavy-path counters
  unsigned* xmaskW = (unsigned*)w; w += 64;
  int* flagW = (int*)w;      w += (size_t)16 * LL * 16 * 4;     // 128 KB one-shot flags

  // buffer 0 of hfrag must be zero (h_0 = 0); counters/flags/masks start at 0
  hipMemsetAsync(hfrag, 0, (size_t)2 * 2 * 64 * 256 * 8 * 2, stream);
  hipMemsetAsync(barW, 0, (size_t)16 * (LL + 1) * 32 * 4, stream);
  hipMemsetAsync(xmaskW, 0, 64, stream);
  hipMemsetAsync(flagW, 0, (size_t)16 * LL * 16 * 4, stream);

  conv_bf16<<<16384, 256, 0, stream>>>(x, xe_bf);
  prep_weights<<<8192, 256, 0, stream>>>(Wih_f, Whh_f, b_f, Wih_b, Whh_b, b_b,
                                         Wih_p, Whh_p, bias_p);
  attn_alpha<<<256, 256, 0, stream>>>(x, tword, W_h, b_tanh, xlen, alphaW);
  gemm_bt<<<dim3(32, 256), 256, 0, stream>>>(xe_bf, Wih_p, Pbuf);

  {
    const u16* Pc = Pbuf;
    const u16* Wc = Whh_p;
    const float* bc = bias_p;
    const float* ac = alphaW;
    const int* lc = xlen;
    u16* hc = hfrag;
    float* cc = ctxb;
    int* brc = barW;
    unsigned* xm = xmaskW;
    int* fl = flagW;
    void* kargs[] = {&Pc, &Wc, &bc, &ac, &lc, &hc, &cc, &brc, &xm, &fl};
    hipLaunchCooperativeKernel((const void*)lstm_persist, dim3(256), dim3(256),
                               kargs, 0, stream);
  }

  head<<<256, 256, 0, stream>>>(ctxb, W_lin, b_lin, W_out, b_out, out);
}